// Round 2
// baseline (369.423 us; speedup 1.0000x reference)
//
#include <hip/hip_runtime.h>

// DeltaQuantLinear: out[t,o] = sum_k x[t,k] * (base[o,k] + (q[o,k]-zp[o])*scale[o]) + bias[o]
// M=8 tokens, N=11008 out rows, K=4096. Memory-bound: 361 MB (w+q) per call.
//
// Design: one wave per 64-thread block, each wave owns RPW=4 full rows.
//   - K split 64-way inside the wave (lane covers k = slice*256 + lane*4, 16 slices)
//   - acc[4][8] in registers; 6-step __shfl_xor butterfly; 32 lanes store directly
//   - NO LDS, NO __syncthreads -> no vmcnt(0)-drain at block end
//   - 2752 blocks x 1 wave: all waves co-resident (~10.75 waves/CU), zero dispatch tail
//   - per slice: 8 HBM loads (w,q; nontemporal) + 8 L2 loads (x) issued back-to-back

#define IN_F    4096
#define OUT_F   11008
#define TOKENS  8
#define RPW     4                   // rows per wave
#define THREADS 64                  // one wave per block
#define NBLOCKS (OUT_F / RPW)       // 2752
#define KSLICE  (IN_F / (64 * 4))   // 16 slices of 256 floats

typedef float vf4 __attribute__((ext_vector_type(4)));
typedef int   vi4 __attribute__((ext_vector_type(4)));

__global__ __launch_bounds__(THREADS, 3)
void DeltaQuantLinear_87540023427416_kernel(
    const float* __restrict__ x,      // [8, 4096]
    const float* __restrict__ w,      // [11008, 4096]
    const int*   __restrict__ q,      // [11008, 4096]
    const float* __restrict__ scales, // [11008]
    const float* __restrict__ zps,    // [11008]
    const float* __restrict__ bias,   // [11008]
    float*       __restrict__ out)    // [8, 11008]
{
    const int lane = threadIdx.x;           // 0..63
    const int r0   = blockIdx.x * RPW;

    // per-row dequant constants: wfull = fma(q, s, w + c0), c0 = -zp*s
    float s[RPW], c0[RPW];
#pragma unroll
    for (int r = 0; r < RPW; ++r) {
        const float sc = scales[r0 + r];
        s[r]  = sc;
        c0[r] = -zps[r0 + r] * sc;
    }

    float acc[RPW][TOKENS];
#pragma unroll
    for (int r = 0; r < RPW; ++r)
#pragma unroll
        for (int t = 0; t < TOKENS; ++t) acc[r][t] = 0.0f;

#pragma unroll 2
    for (int sl = 0; sl < KSLICE; ++sl) {
        const int k = sl * 256 + lane * 4;

        // HBM streams first (longest latency), back-to-back: 8 x 1KB/wave in flight
        vf4 wv[RPW];
        vi4 qv[RPW];
#pragma unroll
        for (int r = 0; r < RPW; ++r) {
            const float* wp = w + (size_t)(r0 + r) * IN_F + k;
            const int*   qp = q + (size_t)(r0 + r) * IN_F + k;
            wv[r] = __builtin_nontemporal_load((const vf4*)wp);
            qv[r] = __builtin_nontemporal_load((const vi4*)qp);
        }

        // x: 128 KB total, L2-resident (no nt hint; we WANT it cached)
        vf4 xr[TOKENS];
#pragma unroll
        for (int t = 0; t < TOKENS; ++t)
            xr[t] = *(const vf4*)(x + t * IN_F + k);

#pragma unroll
        for (int r = 0; r < RPW; ++r) {
#pragma unroll
            for (int j = 0; j < 4; ++j) {
                const float wfull = fmaf((float)qv[r][j], s[r], wv[r][j] + c0[r]);
#pragma unroll
                for (int t = 0; t < TOKENS; ++t)
                    acc[r][t] = fmaf(xr[t][j], wfull, acc[r][t]);
            }
        }
    }

    // full-wave butterfly: every lane ends with the complete sum (192 shfl+add, ~1% of runtime)
#pragma unroll
    for (int i = 0; i < 6; ++i) {
        const int mask = 1 << i;
#pragma unroll
        for (int r = 0; r < RPW; ++r)
#pragma unroll
            for (int t = 0; t < TOKENS; ++t)
                acc[r][t] += __shfl_xor(acc[r][t], mask, 64);
    }

    // 32 lanes store 4 rows x 8 tokens; r fastest -> 4-dword coalesced chunks per token
    if (lane < RPW * TOKENS) {
        const int r = lane & (RPW - 1);
        const int t = lane >> 2;
        const int o = r0 + r;
        out[t * OUT_F + o] = acc[r][t] + bias[o];
    }
}

extern "C" void kernel_launch(void* const* d_in, const int* in_sizes, int n_in,
                              void* d_out, int out_size, void* d_ws, size_t ws_size,
                              hipStream_t stream) {
    const float* x      = (const float*)d_in[0];
    const float* w      = (const float*)d_in[1];
    const int*   q      = (const int*)d_in[2];
    const float* scales = (const float*)d_in[3];
    const float* zps    = (const float*)d_in[4];
    const float* bias   = (const float*)d_in[5];
    float* out = (float*)d_out;

    DeltaQuantLinear_87540023427416_kernel<<<NBLOCKS, THREADS, 0, stream>>>(
        x, w, q, scales, zps, bias, out);
}

// Round 3
// 337.730 us; speedup vs baseline: 1.0938x; 1.0938x over previous
//
#include <hip/hip_runtime.h>

// DeltaQuantLinear: out[t,o] = sum_k x[t,k] * (base[o,k] + (q[o,k]-zp[o])*scale[o]) + bias[o]
// M=8 tokens, N=11008 out rows, K=4096. Memory-bound: 361 MB weights+q per call.
// REVERT to the proven 337.7 µs structure (round-2's wave-per-block variant measured +30 µs
// under a ~2%-slower machine; this resubmission discriminates noise vs regression).

#define IN_F    4096
#define OUT_F   11008
#define TOKENS  8
#define RPB     8                 // output rows per block
#define THREADS 256
#define NBLOCKS (OUT_F / RPB)     // 1376

// clang native vectors: accepted by __builtin_nontemporal_load (HIP_vector_type is not)
typedef float vf4 __attribute__((ext_vector_type(4)));
typedef int   vi4 __attribute__((ext_vector_type(4)));

__global__ __launch_bounds__(THREADS, 2)
void DeltaQuantLinear_87540023427416_kernel(
    const float* __restrict__ x,      // [8, 4096]
    const float* __restrict__ w,      // [11008, 4096]
    const int*   __restrict__ q,      // [11008, 4096]
    const float* __restrict__ scales, // [11008]
    const float* __restrict__ zps,    // [11008]
    const float* __restrict__ bias,   // [11008]
    float*       __restrict__ out)    // [8, 11008]
{
    // reduction scratch: 32 outputs x 256 thread-partials, stride 257 (conflict-free)
    __shared__ float lds[32 * 257];   // 32,896 B
    __shared__ float lds2[32 * 8];    // 1,024 B

    const int tid = threadIdx.x;
    const int o0  = blockIdx.x * RPB;

    // per-row dequant constants (block-uniform -> scalar loads)
    float s[RPB], c0[RPB];
#pragma unroll
    for (int r = 0; r < RPB; ++r) {
        const float sc = scales[o0 + r];
        s[r]  = sc;
        c0[r] = -zps[o0 + r] * sc;   // (q - zp)*s = q*s + c0
    }

    float acc[RPB][TOKENS];
#pragma unroll
    for (int r = 0; r < RPB; ++r)
#pragma unroll
        for (int t = 0; t < TOKENS; ++t) acc[r][t] = 0.0f;

    // Thread owns k = c*1024 + tid*4 + j  (j in 0..3), c in 0..3.
    // Per wave: contiguous 1 KB dwordx4 loads for x, w, q.
#pragma unroll
    for (int c = 0; c < 4; ++c) {
        const int kbase = c * 1024 + tid * 4;

        vf4 xr[TOKENS];
#pragma unroll
        for (int t = 0; t < TOKENS; ++t)
            xr[t] = *(const vf4*)(x + t * IN_F + kbase);

#pragma unroll
        for (int g = 0; g < 2; ++g) {   // rows in groups of 4: 8 loads in flight
            vf4 wv[4];
            vi4 qv[4];
#pragma unroll
            for (int rr = 0; rr < 4; ++rr) {
                const int r = g * 4 + rr;
                const float* wp = w + (size_t)(o0 + r) * IN_F + kbase;
                const int*   qp = q + (size_t)(o0 + r) * IN_F + kbase;
                wv[rr] = __builtin_nontemporal_load((const vf4*)wp);
                qv[rr] = __builtin_nontemporal_load((const vi4*)qp);
            }
#pragma unroll
            for (int rr = 0; rr < 4; ++rr) {
                const int r = g * 4 + rr;
#pragma unroll
                for (int j = 0; j < 4; ++j) {
                    const float wfull = fmaf((float)qv[rr][j], s[r], wv[rr][j] + c0[r]);
#pragma unroll
                    for (int t = 0; t < TOKENS; ++t) {
                        acc[r][t] = fmaf(xr[t][j], wfull, acc[r][t]);
                    }
                }
            }
        }
    }

    // Block reduction: 64 outputs (8 rows x 8 tokens), 256 partials each.
    // Two halves of 4 rows to keep LDS at 33 KB.
#pragma unroll
    for (int h = 0; h < 2; ++h) {
#pragma unroll
        for (int rl = 0; rl < 4; ++rl)
#pragma unroll
            for (int t = 0; t < TOKENS; ++t)
                lds[(rl * 8 + t) * 257 + tid] = acc[h * 4 + rl][t];
        __syncthreads();

        {   // 8 threads per output, each sums 32 partials (conflict-free: stride-257 rows)
            const int l = tid & 31;       // output index within half
            const int p = tid >> 5;       // partial group
            float sum = 0.0f;
            const float* row = &lds[l * 257 + p * 32];
#pragma unroll
            for (int j = 0; j < 32; ++j) sum += row[j];
            lds2[l * 8 + p] = sum;
        }
        __syncthreads();

        if (tid < 32) {
            float tot = 0.0f;
#pragma unroll
            for (int j = 0; j < 8; ++j) tot += lds2[tid * 8 + j];
            const int rl = tid >> 3;
            const int t  = tid & 7;
            const int o  = o0 + h * 4 + rl;
            out[t * OUT_F + o] = tot + bias[o];
        }
        __syncthreads();
    }
}

extern "C" void kernel_launch(void* const* d_in, const int* in_sizes, int n_in,
                              void* d_out, int out_size, void* d_ws, size_t ws_size,
                              hipStream_t stream) {
    const float* x      = (const float*)d_in[0];
    const float* w      = (const float*)d_in[1];
    const int*   q      = (const int*)d_in[2];
    const float* scales = (const float*)d_in[3];
    const float* zps    = (const float*)d_in[4];
    const float* bias   = (const float*)d_in[5];
    float* out = (float*)d_out;

    DeltaQuantLinear_87540023427416_kernel<<<NBLOCKS, THREADS, 0, stream>>>(
        x, w, q, scales, zps, bias, out);
}